// Round 7
// baseline (142.442 us; speedup 1.0000x reference)
//
#include <hip/hip_runtime.h>
#include <hip/hip_bf16.h>
#include <stdint.h>

// RadianceNetwork: 256 independent channel MLPs, B=64.
//   x  = concat(ue[3], view[3], feat[128], nid[1])            -> [64, 135]
//   h1 = relu(x @ W1[c] + b1[c])                              -> [64, 256]
//   h2 = relu(h1 @ W2[c] + b2[c])                             -> [64, 256]
//   o  = h2 @ W3[c] + b3[c]                                   -> [64, 816]
//
// OUTPUT: real components only, fp32: d_out = 6,684,672 fp32 =
// [64][256][408]; out[(m*256+c)*408 + s] = o[m][c][2*s]. (R0-R5 forensics.)
//
// R5: 512thr, 124 VGPR -> 111.9us, latency-bound (15.8% HBM, 21% occ).
// R6: 1024thr + __launch_bounds__(1024,4): compiler crushed VGPR to 64 ->
//     spills (WRITE 27->80MB, FETCH 166->248MB) -> 142us REGRESSION.
// R7: 1024thr, __launch_bounds__(1024) only -> VGPR cap 128 (fits the ~124
//     this code wants), 16 waves/CU, no spills. Single-variable fix.
//
// LDS: 64 KB static. buf0 = h1 (64x512B, XOR-swizzled);
//                    buf1 = union{ x (64x336B) ; h2 (64x512B) }.

#define NCH    256
#define BATCH  64
#define IN_K   135
#define HID    256
#define OUTN   816
#define OUTS   408    // stored real components per (m, c)
#define XPITCHB 336   // bytes per x row (168 bf16; zero-padded k in [135,168))
#define HROWB   512   // bytes per h row (256 bf16, swizzled)
#define NWAVES 16
#define BLOCK  1024

typedef __bf16 bf16x8 __attribute__((ext_vector_type(8)));
typedef float  f32x4  __attribute__((ext_vector_type(4)));

// MFMA 16x16x32 bf16 layouts (HW-verified, learn_hip m89):
//   A: row m = lane&15,  k = (lane>>4)*8 + i   (8 contiguous k -> ds_read_b128)
//   B: col n = lane&15,  k = (lane>>4)*8 + i   (stride-N dword loads from W)
//   D: col n = lane&15,  row m = (lane>>4)*4 + r
template<int K, int N, bool ASWZ, bool RELU>
__device__ __forceinline__ void mlp_layer(
    const char*  __restrict__ A,     // LDS activations (x or swizzled h)
    const float* __restrict__ Wg,    // [K][N] weights for this channel
    const float* __restrict__ bg,    // [N]
    char*        __restrict__ Hout,  // LDS out (RELU path), swizzled pitch 512B
    float*       __restrict__ Gout,  // global fp32 out (final layer), + c*OUTS
    unsigned long long out_sz,
    int wave, int lane)
{
  constexpr int KSTEPS = (K + 31) / 32;
  constexpr int NT = N / 16;
  const int col = lane & 15;
  const int g   = lane >> 4;

  for (int nt = wave; nt < NT; nt += NWAVES) {
    const int n0 = nt * 16 + col;
    const float* wp = Wg + n0;
    f32x4 acc[4] = {};
#pragma unroll
    for (int ks = 0; ks < KSTEPS; ++ks) {
      const int kb = ks * 32 + g * 8;
      float w[8];
#pragma unroll
      for (int i = 0; i < 8; ++i) {
        const int k = kb + i;
        // K%32!=0 only for layer 1 (K=135): predicate tail (matches zero-padded x).
        w[i] = ((K % 32 == 0) || (k < K)) ? wp[(size_t)k * N] : 0.0f;
      }
      bf16x8 bfrag;
#pragma unroll
      for (int i = 0; i < 8; ++i) bfrag[i] = (__bf16)w[i];
#pragma unroll
      for (int mt = 0; mt < 4; ++mt) {
        const int m = mt * 16 + col;
        const uint32_t ab = ASWZ
            ? (uint32_t)m * HROWB + (((uint32_t)(kb * 2)) ^ (((uint32_t)m & 7u) << 4))
            : (uint32_t)m * XPITCHB + (uint32_t)(kb * 2);
        const bf16x8 afrag = *(const bf16x8*)(A + ab);
        acc[mt] = __builtin_amdgcn_mfma_f32_16x16x32_bf16(afrag, bfrag, acc[mt], 0, 0, 0);
      }
    }
    const float bias = bg[n0];
#pragma unroll
    for (int mt = 0; mt < 4; ++mt) {
#pragma unroll
      for (int r = 0; r < 4; ++r) {
        float v = acc[mt][r] + bias;
        const int m = mt * 16 + g * 4 + r;
        if (RELU) {
          v = v > 0.0f ? v : 0.0f;
          *(__bf16*)(Hout + (uint32_t)m * HROWB +
                     (((uint32_t)(n0 * 2)) ^ (((uint32_t)m & 7u) << 4))) = (__bf16)v;
        } else if ((n0 & 1) == 0) {            // real component only
          const unsigned long long oi =
              (unsigned long long)m * (NCH * OUTS) + (unsigned long long)(n0 >> 1);
          if (oi < out_sz) Gout[oi] = v;       // fp32 store, runtime-guarded
        }
      }
    }
  }
}

__global__ __launch_bounds__(BLOCK) void radiance_mlp_kernel(
    const float* __restrict__ ue,   const float* __restrict__ view,
    const float* __restrict__ feat, const int*   __restrict__ ids,
    const float* __restrict__ W1, const float* __restrict__ b1,
    const float* __restrict__ W2, const float* __restrict__ b2,
    const float* __restrict__ W3, const float* __restrict__ b3,
    float* __restrict__ out, unsigned long long out_sz)
{
  __shared__ __attribute__((aligned(16))) char buf0[BATCH * HROWB]; // h1: 32 KB
  __shared__ __attribute__((aligned(16))) char buf1[BATCH * HROWB]; // x then h2: 32 KB

  const int c    = blockIdx.x;
  const int tid  = threadIdx.x;
  const int wave = tid >> 6;
  const int lane = tid & 63;

  // Assemble shared input x -> bf16 in buf1 (pitch 336 B), zero-pad k in [135,168).
  for (int idx = tid; idx < BATCH * (XPITCHB / 2); idx += BLOCK) {
    const int m = idx / (XPITCHB / 2);
    const int k = idx - m * (XPITCHB / 2);
    float v = 0.0f;
    if (k < 3)         v = ue[m * 3 + k];
    else if (k < 6)    v = view[m * 3 + (k - 3)];
    else if (k < 134)  v = feat[m * 128 + (k - 6)];
    else if (k == 134) v = ((float)ids[m] - 1.0f) * (1.0f / 63.0f);
    *(__bf16*)(buf1 + (uint32_t)m * XPITCHB + 2u * (uint32_t)k) = (__bf16)v;
  }
  __syncthreads();

  // L1: reads buf1 (x), writes buf0 (h1)
  mlp_layer<IN_K, HID, false, true>(buf1, W1 + (size_t)c * IN_K * HID,
                                    b1 + (size_t)c * HID, buf0, nullptr, 0, wave, lane);
  __syncthreads();
  // L2: reads buf0 (h1), writes buf1 (h2; x is dead)
  mlp_layer<HID, HID, true, true>(buf0, W2 + (size_t)c * HID * HID,
                                  b2 + (size_t)c * HID, buf1, nullptr, 0, wave, lane);
  __syncthreads();
  // L3: reads buf1 (h2), writes global fp32 real components
  mlp_layer<HID, OUTN, true, false>(buf1, W3 + (size_t)c * HID * OUTN,
                                    b3 + (size_t)c * OUTN, nullptr,
                                    out + (size_t)c * OUTS, out_sz, wave, lane);
}

extern "C" void kernel_launch(void* const* d_in, const int* in_sizes, int n_in,
                              void* d_out, int out_size, void* d_ws, size_t ws_size,
                              hipStream_t stream) {
  const float* ue   = (const float*)d_in[0];
  const float* view = (const float*)d_in[1];
  const float* feat = (const float*)d_in[2];
  const int*   ids  = (const int*)d_in[3];
  const float* W1   = (const float*)d_in[4];
  const float* b1   = (const float*)d_in[5];
  const float* W2   = (const float*)d_in[6];
  const float* b2   = (const float*)d_in[7];
  const float* W3   = (const float*)d_in[8];
  const float* b3   = (const float*)d_in[9];
  float* out = (float*)d_out;

  hipLaunchKernelGGL(radiance_mlp_kernel, dim3(NCH), dim3(BLOCK), 0, stream,
                     ue, view, feat, ids, W1, b1, W2, b2, W3, b3,
                     out, (unsigned long long)out_size);
}

// Round 8
// 106.978 us; speedup vs baseline: 1.3315x; 1.3315x over previous
//
#include <hip/hip_runtime.h>
#include <hip/hip_bf16.h>
#include <stdint.h>

// RadianceNetwork: 256 independent channel MLPs, B=64.
//   x  = concat(ue[3], view[3], feat[128], nid[1])            -> [64, 135]
//   h1 = relu(x @ W1[c] + b1[c])                              -> [64, 256]
//   h2 = relu(h1 @ W2[c] + b2[c])                             -> [64, 256]
//   o  = h2 @ W3[c] + b3[c]                                   -> [64, 816]
// OUTPUT: real components only, fp32 [64][256][408] (R0-R5 forensics).
//
// History: R5 512thr/124VGPR = 111.9us, latency-bound (8 waves/CU, ~8 loads
// in flight/wave). R6/R7: 1024-thr blocks force the 64-VGPR bucket on this
// toolchain (both (1024,4) and bare (1024)) -> spills -> 142us.
// R8: keep 512-thr blocks (known 124-VGPR/no-spill codegen); get 16 waves/CU
// via TWO blocks per CU: each block does HALF THE BATCH (32 rows) of one
// channel. LDS 32KB/block. Channel's two halves are paired on one XCD
// (blockIdx%8 == XCD round-robin) so the duplicated W stream hits L2.

#define NCH    256
#define BATCH  32     // rows per block (half batch)
#define MT     2      // 16-row m-tiles per block
#define IN_K   135
#define HID    256
#define OUTN   816
#define OUTS   408    // stored real components per (m, c)
#define XPITCHB 336   // bytes per x row (168 bf16; zero-padded k in [135,168))
#define HROWB   512   // bytes per h row (256 bf16, swizzled)
#define NWAVES 8
#define BLOCK  512

typedef __bf16 bf16x8 __attribute__((ext_vector_type(8)));
typedef float  f32x4  __attribute__((ext_vector_type(4)));

// MFMA 16x16x32 bf16 layouts (HW-verified, learn_hip m89):
//   A: row m = lane&15,  k = (lane>>4)*8 + i   (8 contiguous k -> ds_read_b128)
//   B: col n = lane&15,  k = (lane>>4)*8 + i   (stride-N dword loads from W)
//   D: col n = lane&15,  row m = (lane>>4)*4 + r
template<int K, int N, bool ASWZ, bool RELU>
__device__ __forceinline__ void mlp_layer(
    const char*  __restrict__ A,     // LDS activations (x or swizzled h), 32 rows
    const float* __restrict__ Wg,    // [K][N] weights for this channel
    const float* __restrict__ bg,    // [N]
    char*        __restrict__ Hout,  // LDS out (RELU path), swizzled pitch 512B
    float*       __restrict__ Gout,  // global fp32 out base (+ c*OUTS)
    unsigned long long out_sz,
    int wave, int lane, int mbase)   // mbase = global row offset (0 or 32)
{
  constexpr int KSTEPS = (K + 31) / 32;
  constexpr int NT = N / 16;
  const int col = lane & 15;
  const int g   = lane >> 4;

  for (int nt = wave; nt < NT; nt += NWAVES) {
    const int n0 = nt * 16 + col;
    const float* wp = Wg + n0;
    f32x4 acc[MT] = {};
#pragma unroll
    for (int ks = 0; ks < KSTEPS; ++ks) {
      const int kb = ks * 32 + g * 8;
      float w[8];
#pragma unroll
      for (int i = 0; i < 8; ++i) {
        const int k = kb + i;
        // K%32!=0 only for layer 1 (K=135): predicate tail (matches zero-padded x).
        w[i] = ((K % 32 == 0) || (k < K)) ? wp[(size_t)k * N] : 0.0f;
      }
      bf16x8 bfrag;
#pragma unroll
      for (int i = 0; i < 8; ++i) bfrag[i] = (__bf16)w[i];
#pragma unroll
      for (int mt = 0; mt < MT; ++mt) {
        const int m = mt * 16 + col;   // local row (0..31)
        const uint32_t ab = ASWZ
            ? (uint32_t)m * HROWB + (((uint32_t)(kb * 2)) ^ (((uint32_t)m & 7u) << 4))
            : (uint32_t)m * XPITCHB + (uint32_t)(kb * 2);
        const bf16x8 afrag = *(const bf16x8*)(A + ab);
        acc[mt] = __builtin_amdgcn_mfma_f32_16x16x32_bf16(afrag, bfrag, acc[mt], 0, 0, 0);
      }
    }
    const float bias = bg[n0];
#pragma unroll
    for (int mt = 0; mt < MT; ++mt) {
#pragma unroll
      for (int r = 0; r < 4; ++r) {
        float v = acc[mt][r] + bias;
        const int m = mt * 16 + g * 4 + r;   // local row
        if (RELU) {
          v = v > 0.0f ? v : 0.0f;
          *(__bf16*)(Hout + (uint32_t)m * HROWB +
                     (((uint32_t)(n0 * 2)) ^ (((uint32_t)m & 7u) << 4))) = (__bf16)v;
        } else if ((n0 & 1) == 0) {          // real component only
          const unsigned long long oi =
              (unsigned long long)(mbase + m) * (NCH * OUTS) +
              (unsigned long long)(n0 >> 1);
          if (oi < out_sz) Gout[oi] = v;     // fp32 store, runtime-guarded
        }
      }
    }
  }
}

__global__ __launch_bounds__(BLOCK) void radiance_mlp_kernel(
    const float* __restrict__ ue,   const float* __restrict__ view,
    const float* __restrict__ feat, const int*   __restrict__ ids,
    const float* __restrict__ W1, const float* __restrict__ b1,
    const float* __restrict__ W2, const float* __restrict__ b2,
    const float* __restrict__ W3, const float* __restrict__ b3,
    float* __restrict__ out, unsigned long long out_sz)
{
  __shared__ __attribute__((aligned(16))) char buf0[BATCH * HROWB]; // h1: 16 KB
  __shared__ __attribute__((aligned(16))) char buf1[BATCH * HROWB]; // x / h2: 16 KB

  // blockIdx -> (channel, batch-half), pairing both halves of a channel on
  // one XCD (dispatch round-robins blockIdx%8 across the 8 XCDs).
  const int i    = blockIdx.x;
  const int xcd  = i & 7;
  const int j    = i >> 3;            // 0..63 within XCD
  const int c    = xcd * 32 + (j >> 1);
  const int half = j & 1;
  const int mbase = half * BATCH;     // 0 or 32

  const int tid  = threadIdx.x;
  const int wave = tid >> 6;
  const int lane = tid & 63;

  // Assemble this half's input rows -> bf16 in buf1 (pitch 336 B),
  // zero-pad k in [135,168).
  for (int idx = tid; idx < BATCH * (XPITCHB / 2); idx += BLOCK) {
    const int m  = idx / (XPITCHB / 2);       // local row
    const int k  = idx - m * (XPITCHB / 2);
    const int mg = mbase + m;                 // global row
    float v = 0.0f;
    if (k < 3)         v = ue[mg * 3 + k];
    else if (k < 6)    v = view[mg * 3 + (k - 3)];
    else if (k < 134)  v = feat[mg * 128 + (k - 6)];
    else if (k == 134) v = ((float)ids[mg] - 1.0f) * (1.0f / 63.0f);
    *(__bf16*)(buf1 + (uint32_t)m * XPITCHB + 2u * (uint32_t)k) = (__bf16)v;
  }
  __syncthreads();

  // L1: reads buf1 (x), writes buf0 (h1)
  mlp_layer<IN_K, HID, false, true>(buf1, W1 + (size_t)c * IN_K * HID,
                                    b1 + (size_t)c * HID, buf0, nullptr, 0,
                                    wave, lane, mbase);
  __syncthreads();
  // L2: reads buf0 (h1), writes buf1 (h2; x is dead)
  mlp_layer<HID, HID, true, true>(buf0, W2 + (size_t)c * HID * HID,
                                  b2 + (size_t)c * HID, buf1, nullptr, 0,
                                  wave, lane, mbase);
  __syncthreads();
  // L3: reads buf1 (h2), writes global fp32 real components
  mlp_layer<HID, OUTN, true, false>(buf1, W3 + (size_t)c * HID * OUTN,
                                    b3 + (size_t)c * OUTN, nullptr,
                                    out + (size_t)c * OUTS, out_sz,
                                    wave, lane, mbase);
}

extern "C" void kernel_launch(void* const* d_in, const int* in_sizes, int n_in,
                              void* d_out, int out_size, void* d_ws, size_t ws_size,
                              hipStream_t stream) {
  const float* ue   = (const float*)d_in[0];
  const float* view = (const float*)d_in[1];
  const float* feat = (const float*)d_in[2];
  const int*   ids  = (const int*)d_in[3];
  const float* W1   = (const float*)d_in[4];
  const float* b1   = (const float*)d_in[5];
  const float* W2   = (const float*)d_in[6];
  const float* b2   = (const float*)d_in[7];
  const float* W3   = (const float*)d_in[8];
  const float* b3   = (const float*)d_in[9];
  float* out = (float*)d_out;

  hipLaunchKernelGGL(radiance_mlp_kernel, dim3(NCH * 2), dim3(BLOCK), 0, stream,
                     ue, view, feat, ids, W1, b1, W2, b2, W3, b3,
                     out, (unsigned long long)out_size);
}

// Round 9
// 93.285 us; speedup vs baseline: 1.5270x; 1.1468x over previous
//
#include <hip/hip_runtime.h>
#include <hip/hip_bf16.h>
#include <stdint.h>

// RadianceNetwork: 256 independent channel MLPs, B=64.
//   x  = concat(ue[3], view[3], feat[128], nid[1])  -> [64, 135]
//   h1 = relu(x @ W1[c] + b1[c])                    -> [64, 256]
//   h2 = relu(h1 @ W2[c] + b2[c])                   -> [64, 256]
//   o  = h2 @ W3[c] + b3[c]                         -> [64, 816]
// OUTPUT: real components only, fp32 [64][256][408] (R0-R5 forensics).
//
// R8 (107us) was latency-bound on per-lane strided weight loads (~1 load in
// flight/wave avg; 60-VGPR codegen can't keep 8 addr+data pairs live).
// R9: block-cooperative double-buffered W staging through LDS:
//   - coalesced dwordx4 global loads (64B/thread/tile), issued 1 tile ahead
//   - in-register 4x4 transpose -> bf16 -> ds_write_b64 into k-major
//     Wlds[n][kk] (row=64B) with 16B XOR swizzle (n>>2&3)<<4
//   - B-fragment = ONE ds_read_b128 (~2-way conflict, free)
// LDS: h1 16K + {x|h2} 16K + Wbuf 2x16K = 64 KB -> 2 blocks/CU.
// Grid: 512 blocks = (channel, batch-half), halves paired per XCD (R8).

#define NCH    256
#define BATCH  32     // rows per block (half batch)
#define MT     2      // 16-row m-tiles per block
#define IN_K   135
#define HID    256
#define OUTN   816
#define OUTS   408    // stored real components per (m, c)
#define XPITCHB 336   // bytes per x row (168 bf16; zero-padded k in [135,168))
#define HROWB   512   // bytes per h row (256 bf16, swizzled)
#define NWAVES 8
#define BLOCK  512

typedef __bf16 bf16x8 __attribute__((ext_vector_type(8)));
typedef float  f32x4  __attribute__((ext_vector_type(4)));

// W-tile LDS addressing: k-major rows, row n = 64 B (32 kk x bf16),
// XOR-swizzled at 16B granularity so frag reads spread banks.
__device__ __forceinline__ uint32_t wswz(int n, uint32_t kkbyte) {
  return (uint32_t)n * 64u + (kkbyte ^ ((((uint32_t)n >> 2) & 3u) << 4));
}

// Issue coalesced loads for one W k-tile (32 k x NCACT n at nc0).
// Thread t: rows kk0..kk0+3 (kk0 = wave*4), cols c4..c4+3 (c4 = (t&63)*4).
template<int K, int NSRC, int NCACT>
__device__ __forceinline__ void stage_issue(const float* __restrict__ Wg,
                                            int kt, int nc0, int tid, f32x4 ld[4]) {
  const int kk0 = (tid >> 6) * 4;
  const int c4  = (tid & 63) * 4;
  if (c4 < NCACT) {
#pragma unroll
    for (int r = 0; r < 4; ++r) {
      const int k = kt * 32 + kk0 + r;     // uniform per wave -> scalar branch
      if ((K % 32 == 0) || (k < K))
        ld[r] = *(const f32x4*)(Wg + (size_t)k * NSRC + nc0 + c4);
      else
        ld[r] = (f32x4){0.f, 0.f, 0.f, 0.f};
    }
  }
}

// 4x4 in-register transpose -> bf16 -> 4x ds_write_b64 (k-contiguous quads).
template<int NCACT>
__device__ __forceinline__ void stage_write(char* __restrict__ Wb, int tid,
                                            const f32x4 ld[4]) {
  const int kk0 = (tid >> 6) * 4;
  const int c4  = (tid & 63) * 4;
  if (c4 < NCACT) {
#pragma unroll
    for (int j = 0; j < 4; ++j) {
      union { __bf16 h[4]; uint2 u; } pk;
      pk.h[0] = (__bf16)ld[0][j];
      pk.h[1] = (__bf16)ld[1][j];
      pk.h[2] = (__bf16)ld[2][j];
      pk.h[3] = (__bf16)ld[3][j];
      *(uint2*)(Wb + wswz(c4 + j, (uint32_t)(kk0 * 2))) = pk.u;
    }
  }
}

// One N-chunk of one layer: acc over KT k-tiles with double-buffered W staging.
// MFMA 16x16x32 bf16 (layouts HW-verified, learn_hip m89):
//   A: row m=lane&15, k=(lane>>4)*8+i ; B: col n=lane&15, same k
//   D: col n=lane&15, row m=(lane>>4)*4+r
template<int K, int KT, int NSRC, int NCT, bool ASWZ, bool RELU>
__device__ __forceinline__ void chunk_layer(
    const char*  __restrict__ A,     // LDS activations (x or swizzled h)
    const float* __restrict__ Wg,    // [K][NSRC] weights, channel base
    const float* __restrict__ bg,    // bias, channel base (layer-wide)
    char*        __restrict__ Hout,  // LDS out (RELU), swizzled pitch 512B
    float*       __restrict__ Gout,  // global out base (+c*OUTS)
    unsigned long long out_sz, int nc0,
    char* __restrict__ Wb0, char* __restrict__ Wb1,
    int tid, int wave, int lane, int mbase)
{
  constexpr int NTPW = (NCT + NWAVES - 1) / NWAVES;  // n-tiles per wave
  const int col = lane & 15;
  const int g   = lane >> 4;

  f32x4 acc[NTPW][MT] = {};
  f32x4 ld[4];

  // prologue: stage k-tile 0 (latency exposed once per chunk)
  stage_issue<K, NSRC, NCT * 16>(Wg, 0, nc0, tid, ld);
  stage_write<NCT * 16>(Wb0, tid, ld);

  for (int kt = 0; kt < KT; ++kt) {
    char* Wb  = (kt & 1) ? Wb1 : Wb0;
    char* Wbn = (kt & 1) ? Wb0 : Wb1;
    const bool more = (kt + 1 < KT);
    if (more) stage_issue<K, NSRC, NCT * 16>(Wg, kt + 1, nc0, tid, ld);  // in flight across compute
    __syncthreads();   // staging of Wb(kt) visible to all
    const int kb = kt * 32 + g * 8;
#pragma unroll
    for (int li = 0; li < NTPW; ++li) {
      const int nt = wave + li * NWAVES;
      if ((NCT % NWAVES == 0) || (nt < NCT)) {
        const int nl = nt * 16 + col;
        const bf16x8 bfrag = *(const bf16x8*)(Wb + wswz(nl, (uint32_t)(g * 16)));
#pragma unroll
        for (int mt = 0; mt < MT; ++mt) {
          const int m = mt * 16 + col;
          const uint32_t ab = ASWZ
              ? (uint32_t)m * HROWB + (((uint32_t)(kb * 2)) ^ (((uint32_t)m & 7u) << 4))
              : (uint32_t)m * XPITCHB + (uint32_t)(kb * 2);
          const bf16x8 afrag = *(const bf16x8*)(A + ab);
          acc[li][mt] = __builtin_amdgcn_mfma_f32_16x16x32_bf16(afrag, bfrag, acc[li][mt], 0, 0, 0);
        }
      }
    }
    if (more) stage_write<NCT * 16>(Wbn, tid, ld);  // other buffer; next BAR orders reads
  }

  // epilogue: bias (+relu->LDS | even-col fp32->global)
#pragma unroll
  for (int li = 0; li < NTPW; ++li) {
    const int nt = wave + li * NWAVES;
    if ((NCT % NWAVES == 0) || (nt < NCT)) {
      const int n = nc0 + nt * 16 + col;   // layer-wide col
      const float bias = bg[n];
#pragma unroll
      for (int mt = 0; mt < MT; ++mt) {
#pragma unroll
        for (int r = 0; r < 4; ++r) {
          float v = acc[li][mt][r] + bias;
          const int m = mt * 16 + g * 4 + r;   // local row
          if (RELU) {
            v = v > 0.f ? v : 0.f;
            *(__bf16*)(Hout + (uint32_t)m * HROWB +
                       (((uint32_t)(n * 2)) ^ (((uint32_t)m & 7u) << 4))) = (__bf16)v;
          } else if ((n & 1) == 0) {           // real component only
            const unsigned long long oi =
                (unsigned long long)(mbase + m) * (NCH * OUTS) +
                (unsigned long long)(n >> 1);
            if (oi < out_sz) Gout[oi] = v;
          }
        }
      }
    }
  }
}

__global__ __launch_bounds__(BLOCK) void radiance_mlp_kernel(
    const float* __restrict__ ue,   const float* __restrict__ view,
    const float* __restrict__ feat, const int*   __restrict__ ids,
    const float* __restrict__ W1, const float* __restrict__ b1,
    const float* __restrict__ W2, const float* __restrict__ b2,
    const float* __restrict__ W3, const float* __restrict__ b3,
    float* __restrict__ out, unsigned long long out_sz)
{
  __shared__ __attribute__((aligned(16))) char buf0[BATCH * HROWB];  // h1: 16 KB
  __shared__ __attribute__((aligned(16))) char buf1[BATCH * HROWB];  // x / h2: 16 KB
  __shared__ __attribute__((aligned(16))) char wbuf[2][256 * 64];    // W dbuf: 32 KB

  // blockIdx -> (channel, batch-half); halves paired per XCD (blockIdx%8 rr).
  const int i     = blockIdx.x;
  const int xcd   = i & 7;
  const int j     = i >> 3;
  const int c     = xcd * 32 + (j >> 1);
  const int mbase = (j & 1) * BATCH;

  const int tid  = threadIdx.x;
  const int wave = tid >> 6;
  const int lane = tid & 63;

  // Stage this half's input rows -> bf16 in buf1 (pitch 336B), zero-pad [135,168).
  for (int idx = tid; idx < BATCH * (XPITCHB / 2); idx += BLOCK) {
    const int m  = idx / (XPITCHB / 2);
    const int k  = idx - m * (XPITCHB / 2);
    const int mg = mbase + m;
    float v = 0.0f;
    if (k < 3)         v = ue[mg * 3 + k];
    else if (k < 6)    v = view[mg * 3 + (k - 3)];
    else if (k < 134)  v = feat[mg * 128 + (k - 6)];
    else if (k == 134) v = ((float)ids[mg] - 1.0f) * (1.0f / 63.0f);
    *(__bf16*)(buf1 + (uint32_t)m * XPITCHB + 2u * (uint32_t)k) = (__bf16)v;
  }
  __syncthreads();

  // L1: x(buf1) -> h1(buf0).  K=135 (5 k-tiles, tail predicated), N=256.
  chunk_layer<IN_K, 5, HID, 16, false, true>(
      buf1, W1 + (size_t)c * IN_K * HID, b1 + (size_t)c * HID,
      buf0, nullptr, 0, 0, wbuf[0], wbuf[1], tid, wave, lane, mbase);
  __syncthreads();

  // L2: h1(buf0) -> h2(buf1).  K=256, N=256.
  chunk_layer<HID, 8, HID, 16, true, true>(
      buf0, W2 + (size_t)c * HID * HID, b2 + (size_t)c * HID,
      buf1, nullptr, 0, 0, wbuf[0], wbuf[1], tid, wave, lane, mbase);
  __syncthreads();

  // L3: h2(buf1) -> out.  K=256, N=816 in chunks {256,256,256,48}.
  const float* W3c = W3 + (size_t)c * HID * OUTN;
  const float* b3c = b3 + (size_t)c * OUTN;
  float* outc = out + (size_t)c * OUTS;
  chunk_layer<HID, 8, OUTN, 16, true, false>(
      buf1, W3c, b3c, nullptr, outc, out_sz, 0,   wbuf[0], wbuf[1], tid, wave, lane, mbase);
  __syncthreads();
  chunk_layer<HID, 8, OUTN, 16, true, false>(
      buf1, W3c, b3c, nullptr, outc, out_sz, 256, wbuf[0], wbuf[1], tid, wave, lane, mbase);
  __syncthreads();
  chunk_layer<HID, 8, OUTN, 16, true, false>(
      buf1, W3c, b3c, nullptr, outc, out_sz, 512, wbuf[0], wbuf[1], tid, wave, lane, mbase);
  __syncthreads();
  chunk_layer<HID, 8, OUTN, 3, true, false>(
      buf1, W3c, b3c, nullptr, outc, out_sz, 768, wbuf[0], wbuf[1], tid, wave, lane, mbase);
}

extern "C" void kernel_launch(void* const* d_in, const int* in_sizes, int n_in,
                              void* d_out, int out_size, void* d_ws, size_t ws_size,
                              hipStream_t stream) {
  const float* ue   = (const float*)d_in[0];
  const float* view = (const float*)d_in[1];
  const float* feat = (const float*)d_in[2];
  const int*   ids  = (const int*)d_in[3];
  const float* W1   = (const float*)d_in[4];
  const float* b1   = (const float*)d_in[5];
  const float* W2   = (const float*)d_in[6];
  const float* b2   = (const float*)d_in[7];
  const float* W3   = (const float*)d_in[8];
  const float* b3   = (const float*)d_in[9];
  float* out = (float*)d_out;

  hipLaunchKernelGGL(radiance_mlp_kernel, dim3(NCH * 2), dim3(BLOCK), 0, stream,
                     ue, view, feat, ids, W1, b1, W2, b2, W3, b3,
                     out, (unsigned long long)out_size);
}